// Round 6
// baseline (6851.054 us; speedup 1.0000x reference)
//
#include <hip/hip_runtime.h>
#include <cstdint>
#include <cstddef>

// RNNLayer: B=64, T=1024, IN=512, H=512, fp32 in/out.
// Phase 1: Wx = X @ W_w^T + (W_b + U_b)  (f16 MFMA GEMM) -> d_out.
// Phase 2: MFMA scan. 4 WGs x 512 threads; each WG owns 16 batches on one CU.
//   H_new[16,512] = tanh(Wx + H_old @ U^T) via mfma_f32_16x16x32_f16.
//   U: 12 k-steps reg-resident B-frags, 4 k-steps in 128KB swizzled LDS.
//   H: 16KB swizzled LDS, single-buffered, 2 barriers/step.
// Round-6 changes (vs round 5):
//   * Wx(t+1) prefetched BEFORE h(t) global stores -> vmcnt wait at tanh is
//     counted (16), never drains the store queue (was the dominant stall).
//   * 2x t-loop unroll: wx/wxn double-buffer with zero register copies,
//     all array indices compile-time.
//   * tanh via exp2f: t=exp2(-2*log2e*|a|), r=(1-t)/(1+t), copysign.

#define T_STEPS 1024

using f16 = _Float16;
typedef f16  f16x2 __attribute__((ext_vector_type(2)));
typedef f16  f16x8 __attribute__((ext_vector_type(8)));
typedef float f32x4 __attribute__((ext_vector_type(4)));

static __device__ __forceinline__ f16x8 cvt8(float4 v0, float4 v1) {
    return (f16x8){ (f16)v0.x, (f16)v0.y, (f16)v0.z, (f16)v0.w,
                    (f16)v1.x, (f16)v1.y, (f16)v1.z, (f16)v1.w };
}

// ---------------------------------------------------------------------------
// Kernel 1: Wx GEMM (bias includes U_b). Unchanged (works, ~90us).
// ---------------------------------------------------------------------------
__global__ __launch_bounds__(256, 2)
void gemm_wx(const float* __restrict__ X, const float* __restrict__ W,
             const float* __restrict__ Wb, const float* __restrict__ Ub,
             float* __restrict__ out) {
    __shared__ __align__(16) char Al[128 * 128];
    __shared__ __align__(16) char Bl[128 * 128];

    const int tid  = threadIdx.x;
    const int lane = tid & 63;
    const int wid  = tid >> 6;
    const int wm   = wid & 1;
    const int wn   = wid >> 1;
    const int m0   = blockIdx.x * 128;
    const int n0   = blockIdx.y * 128;

    f32x4 acc[4][4] = {};

    for (int kt = 0; kt < 512; kt += 64) {
        __syncthreads();
#pragma unroll
        for (int i = 0; i < 4; ++i) {
            const int id   = tid + i * 256;
            const int row  = id >> 3;
            const int slot = id & 7;
            const float4* pa = reinterpret_cast<const float4*>(
                X + (size_t)(m0 + row) * 512 + kt + slot * 8);
            const float4* pb = reinterpret_cast<const float4*>(
                W + (size_t)(n0 + row) * 512 + kt + slot * 8);
            f16x8 va = cvt8(pa[0], pa[1]);
            f16x8 vb = cvt8(pb[0], pb[1]);
            const int cb = (slot * 16) ^ ((row & 7) << 4);
            *reinterpret_cast<f16x8*>(Al + row * 128 + cb) = va;
            *reinterpret_cast<f16x8*>(Bl + row * 128 + cb) = vb;
        }
        __syncthreads();

#pragma unroll
        for (int kk = 0; kk < 2; ++kk) {
            f16x8 af[4], bf[4];
#pragma unroll
            for (int mi = 0; mi < 4; ++mi) {
                const int r  = wm * 64 + mi * 16 + (lane & 15);
                const int cb = (kk * 64 + ((lane >> 4) * 16)) ^ ((r & 7) << 4);
                af[mi] = *reinterpret_cast<const f16x8*>(Al + r * 128 + cb);
            }
#pragma unroll
            for (int ni = 0; ni < 4; ++ni) {
                const int r  = wn * 64 + ni * 16 + (lane & 15);
                const int cb = (kk * 64 + ((lane >> 4) * 16)) ^ ((r & 7) << 4);
                bf[ni] = *reinterpret_cast<const f16x8*>(Bl + r * 128 + cb);
            }
#pragma unroll
            for (int mi = 0; mi < 4; ++mi)
#pragma unroll
                for (int ni = 0; ni < 4; ++ni)
                    acc[mi][ni] = __builtin_amdgcn_mfma_f32_16x16x32_f16(
                        af[mi], bf[ni], acc[mi][ni], 0, 0, 0);
        }
    }

#pragma unroll
    for (int ni = 0; ni < 4; ++ni) {
        const int col  = n0 + wn * 64 + ni * 16 + (lane & 15);
        const float bias = Wb[col] + Ub[col];
#pragma unroll
        for (int mi = 0; mi < 4; ++mi) {
            const int rowb = m0 + wm * 64 + mi * 16 + ((lane >> 4) * 4);
#pragma unroll
            for (int e = 0; e < 4; ++e)
                out[(size_t)(rowb + e) * 512 + col] = acc[mi][ni][e] + bias;
        }
    }
}

// ---------------------------------------------------------------------------
// Kernel 2: MFMA scan. Fragment layouts as validated by gemm_wx:
//   A-frag: row = lane&15, k = (lane>>4)*8 + e (8 contiguous f16)
//   B-frag: row(n) = lane&15, k same
//   D:      col(n) = lane&15, row(m) = (lane>>4)*4 + e
// ---------------------------------------------------------------------------
__global__ __launch_bounds__(512, 2)
void rnn_scan(float* __restrict__ out, const float* __restrict__ h0,
              const float* __restrict__ Uw) {
    __shared__ __align__(16) char Ul[512 * 256];   // U[n][k=384..512) f16, 128KB
    __shared__ __align__(16) char Hs[16 * 1024];   // H[m][k] f16, 16KB

    const int tid  = threadIdx.x;
    const int wid  = tid >> 6;       // wave 0..7
    const int lane = tid & 63;
    const int l15  = lane & 15;
    const int l4   = lane >> 4;
    const int n0w  = wid * 64;       // this wave's N-range (4 tiles of 16)
    const int b0   = blockIdx.x * 16;
    const int aswz = (l15 & 7) << 4;

    // ---- U tail (k in [384,512)) -> LDS: 128 f16 = 256B = 16 x 8-float chunks.
    {
        const float4* src = reinterpret_cast<const float4*>(Uw + (size_t)tid * 512 + 384);
        const int sw = (tid & 7) << 4;
#pragma unroll
        for (int i = 0; i < 16; ++i) {
            f16x8 w = cvt8(src[2 * i], src[2 * i + 1]);
            *reinterpret_cast<f16x8*>(Ul + tid * 256 + ((16 * i) ^ sw)) = w;
        }
    }

    // ---- U main (k<384) -> reg B-fragments: u[kk][nt], kk=0..11, nt=0..3.
    f16x8 u[12][4];
#pragma unroll
    for (int kk = 0; kk < 12; ++kk)
#pragma unroll
        for (int nt = 0; nt < 4; ++nt) {
            const float4* p = reinterpret_cast<const float4*>(
                Uw + (size_t)(n0w + nt * 16 + l15) * 512 + kk * 32 + l4 * 8);
            u[kk][nt] = cvt8(p[0], p[1]);
        }

    // ---- h_0 -> Hs (thread tid: batch m=tid>>5, 16-f16 chunk c=tid&31)
    {
        const int m = tid >> 5, c = tid & 31;
        const float4* p = reinterpret_cast<const float4*>(
            h0 + (size_t)(b0 + m) * 512 + c * 16);
        f16x8 w0 = cvt8(p[0], p[1]);
        f16x8 w1 = cvt8(p[2], p[3]);
        const int mb = m * 1024, sw = (m & 7) << 4;
        *reinterpret_cast<f16x8*>(Hs + mb + ((c * 32) ^ sw)) = w0;
        *reinterpret_cast<f16x8*>(Hs + mb + ((c * 32 + 16) ^ sw)) = w1;
    }

    // ---- per-lane byte offsets into out, one per m-row e (batch m = l4*4+e).
    float* const outg = out + (size_t)b0 * (T_STEPS * 512);
    int offe[4];
#pragma unroll
    for (int e = 0; e < 4; ++e)
        offe[e] = ((l4 * 4 + e) * (T_STEPS * 512) + (n0w + l15)) * 4;

    // ---- preload Wx row 0 (gemm_wx completed; same stream).
    float wxA[4][4], wxB[4][4];
#pragma unroll
    for (int e = 0; e < 4; ++e) {
        const float* pe = reinterpret_cast<const float*>(
            reinterpret_cast<const char*>(outg) + offe[e]);
#pragma unroll
        for (int nt = 0; nt < 4; ++nt)
            wxA[nt][e] = pe[nt * 16];
    }

    __syncthreads();

    const float C2L = -2.8853900817779268f;   // -2*log2(e)

    // One scan step. WXIN: this step's Wx (in regs). WXOUT: next step's Wx,
    // prefetched BEFORE the h stores so the vmcnt wait at the next tanh is
    // counted (never drains the store queue).
#define SCAN_STEP(T_CUR, WXIN, WXOUT)                                          \
    {                                                                          \
        f32x4 acc[4];                                                          \
        _Pragma("unroll")                                                      \
        for (int nt = 0; nt < 4; ++nt) acc[nt] = (f32x4){0.f, 0.f, 0.f, 0.f};  \
        _Pragma("unroll")                                                      \
        for (int kk = 0; kk < 16; ++kk) {                                      \
            const f16x8 a = *reinterpret_cast<const f16x8*>(                   \
                Hs + l15 * 1024 + ((kk * 64 + l4 * 16) ^ aswz));               \
            if (kk < 12) {                                                     \
                _Pragma("unroll")                                              \
                for (int nt = 0; nt < 4; ++nt)                                 \
                    acc[nt] = __builtin_amdgcn_mfma_f32_16x16x32_f16(          \
                        a, u[kk][nt], acc[nt], 0, 0, 0);                       \
            } else {                                                           \
                _Pragma("unroll")                                              \
                for (int nt = 0; nt < 4; ++nt) {                               \
                    const f16x8 bb = *reinterpret_cast<const f16x8*>(          \
                        Ul + (size_t)(n0w + nt * 16 + l15) * 256 +             \
                        (((kk - 12) * 64 + l4 * 16) ^ aswz));                  \
                    acc[nt] = __builtin_amdgcn_mfma_f32_16x16x32_f16(          \
                        a, bb, acc[nt], 0, 0, 0);                              \
                }                                                              \
            }                                                                  \
        }                                                                      \
        /* tanh: t=exp2(-2log2e*|a|), r=(1-t)/(1+t), restore sign */           \
        float hv[4][4];                                                        \
        _Pragma("unroll")                                                      \
        for (int nt = 0; nt < 4; ++nt)                                         \
            _Pragma("unroll")                                                  \
            for (int e = 0; e < 4; ++e) {                                      \
                const float aa = acc[nt][e] + WXIN[nt][e];                     \
                const float tt = exp2f(C2L * fabsf(aa));                       \
                const float r  = (1.0f - tt) / (1.0f + tt);                    \
                hv[nt][e] = copysignf(r, aa);                                  \
            }                                                                  \
        /* prefetch next step's Wx FIRST (older than stores in vmcnt queue) */ \
        if ((T_CUR) < T_STEPS - 1) {                                           \
            _Pragma("unroll")                                                  \
            for (int e = 0; e < 4; ++e) {                                      \
                const float* pe = reinterpret_cast<const float*>(              \
                    reinterpret_cast<const char*>(outg) + offe[e] + 2048);     \
                _Pragma("unroll")                                              \
                for (int nt = 0; nt < 4; ++nt)                                 \
                    WXOUT[nt][e] = pe[nt * 16];                                \
            }                                                                  \
        }                                                                      \
        __builtin_amdgcn_sched_barrier(0);                                     \
        /* h(t) -> out (overwrites consumed Wx row) */                         \
        _Pragma("unroll")                                                      \
        for (int e = 0; e < 4; ++e) {                                          \
            float* pe = reinterpret_cast<float*>(                              \
                reinterpret_cast<char*>(outg) + offe[e]);                      \
            _Pragma("unroll")                                                  \
            for (int nt = 0; nt < 4; ++nt)                                     \
                pe[nt * 16] = hv[nt][e];                                       \
            offe[e] += 2048;                                                   \
        }                                                                      \
        /* barrier B: all A-frag reads done -> safe to overwrite Hs */         \
        __builtin_amdgcn_sched_barrier(0);                                     \
        __builtin_amdgcn_s_barrier();                                          \
        __builtin_amdgcn_sched_barrier(0);                                     \
        /* H(t) -> Hs: lane holds rows m=l4*4+e, col j=n0w+nt*16+l15 */        \
        _Pragma("unroll")                                                      \
        for (int nt = 0; nt < 4; ++nt) {                                       \
            const int j2 = 2 * (n0w + nt * 16 + l15);                          \
            _Pragma("unroll")                                                  \
            for (int e = 0; e < 4; ++e) {                                      \
                const int m = l4 * 4 + e;                                      \
                *reinterpret_cast<f16*>(                                       \
                    Hs + m * 1024 + (j2 ^ ((m & 7) << 4))) = (f16)hv[nt][e];   \
            }                                                                  \
        }                                                                      \
        /* barrier A': H(t) visible; vmcnt NOT drained (stores in flight) */   \
        asm volatile("s_waitcnt lgkmcnt(0)" ::: "memory");                     \
        __builtin_amdgcn_s_barrier();                                          \
        __builtin_amdgcn_sched_barrier(0);                                     \
    }

    for (int t = 0; t < T_STEPS; t += 2) {
        SCAN_STEP(t,     wxA, wxB);
        SCAN_STEP(t + 1, wxB, wxA);
    }
#undef SCAN_STEP
}

// ---------------------------------------------------------------------------
extern "C" void kernel_launch(void* const* d_in, const int* in_sizes, int n_in,
                              void* d_out, int out_size, void* d_ws, size_t ws_size,
                              hipStream_t stream) {
    const float* X  = (const float*)d_in[0];
    const float* h0 = (const float*)d_in[1];
    const float* Ww = (const float*)d_in[2];
    const float* Wb = (const float*)d_in[3];
    const float* Uw = (const float*)d_in[4];
    const float* Ub = (const float*)d_in[5];
    float* out = (float*)d_out;

    gemm_wx<<<dim3(512, 4), dim3(256), 0, stream>>>(X, Ww, Wb, Ub, out);
    rnn_scan<<<dim3(4), dim3(512), 0, stream>>>(out, h0, Uw);
}

// Round 7
// 5029.192 us; speedup vs baseline: 1.3623x; 1.3623x over previous
//
#include <hip/hip_runtime.h>
#include <cstdint>
#include <cstddef>

// RNNLayer: B=64, T=1024, IN=512, H=512, fp32 in/out.
// Phase 1: Wx = X @ W_w^T + (W_b + U_b)  (f16 MFMA GEMM) -> d_out.
// Phase 2: MFMA scan. 4 WGs x 512 threads; each WG owns 16 batches on one CU.
//   H_new[16,512] = tanh(Wx + H_old @ U^T) via mfma_f32_16x16x32_f16.
//   U: 12 k-steps reg-resident B-frags, 4 k-steps in 128KB swizzled LDS.
//   H: DOUBLE-buffered 2x16KB swizzled LDS -> ONE barrier per step
//      (round 5 had 2; round 6's sched_barrier pinning regressed and is gone).
//   LDS total = 128K + 32K = 160KB (full pool, 1 WG/CU).

#define T_STEPS 1024

using f16 = _Float16;
typedef f16  f16x2 __attribute__((ext_vector_type(2)));
typedef f16  f16x8 __attribute__((ext_vector_type(8)));
typedef float f32x4 __attribute__((ext_vector_type(4)));

static __device__ __forceinline__ f16x8 cvt8(float4 v0, float4 v1) {
    return (f16x8){ (f16)v0.x, (f16)v0.y, (f16)v0.z, (f16)v0.w,
                    (f16)v1.x, (f16)v1.y, (f16)v1.z, (f16)v1.w };
}

// ---------------------------------------------------------------------------
// Kernel 1: Wx GEMM (bias includes U_b). Unchanged.
// ---------------------------------------------------------------------------
__global__ __launch_bounds__(256, 2)
void gemm_wx(const float* __restrict__ X, const float* __restrict__ W,
             const float* __restrict__ Wb, const float* __restrict__ Ub,
             float* __restrict__ out) {
    __shared__ __align__(16) char Al[128 * 128];
    __shared__ __align__(16) char Bl[128 * 128];

    const int tid  = threadIdx.x;
    const int lane = tid & 63;
    const int wid  = tid >> 6;
    const int wm   = wid & 1;
    const int wn   = wid >> 1;
    const int m0   = blockIdx.x * 128;
    const int n0   = blockIdx.y * 128;

    f32x4 acc[4][4] = {};

    for (int kt = 0; kt < 512; kt += 64) {
        __syncthreads();
#pragma unroll
        for (int i = 0; i < 4; ++i) {
            const int id   = tid + i * 256;
            const int row  = id >> 3;
            const int slot = id & 7;
            const float4* pa = reinterpret_cast<const float4*>(
                X + (size_t)(m0 + row) * 512 + kt + slot * 8);
            const float4* pb = reinterpret_cast<const float4*>(
                W + (size_t)(n0 + row) * 512 + kt + slot * 8);
            f16x8 va = cvt8(pa[0], pa[1]);
            f16x8 vb = cvt8(pb[0], pb[1]);
            const int cb = (slot * 16) ^ ((row & 7) << 4);
            *reinterpret_cast<f16x8*>(Al + row * 128 + cb) = va;
            *reinterpret_cast<f16x8*>(Bl + row * 128 + cb) = vb;
        }
        __syncthreads();

#pragma unroll
        for (int kk = 0; kk < 2; ++kk) {
            f16x8 af[4], bf[4];
#pragma unroll
            for (int mi = 0; mi < 4; ++mi) {
                const int r  = wm * 64 + mi * 16 + (lane & 15);
                const int cb = (kk * 64 + ((lane >> 4) * 16)) ^ ((r & 7) << 4);
                af[mi] = *reinterpret_cast<const f16x8*>(Al + r * 128 + cb);
            }
#pragma unroll
            for (int ni = 0; ni < 4; ++ni) {
                const int r  = wn * 64 + ni * 16 + (lane & 15);
                const int cb = (kk * 64 + ((lane >> 4) * 16)) ^ ((r & 7) << 4);
                bf[ni] = *reinterpret_cast<const f16x8*>(Bl + r * 128 + cb);
            }
#pragma unroll
            for (int mi = 0; mi < 4; ++mi)
#pragma unroll
                for (int ni = 0; ni < 4; ++ni)
                    acc[mi][ni] = __builtin_amdgcn_mfma_f32_16x16x32_f16(
                        af[mi], bf[ni], acc[mi][ni], 0, 0, 0);
        }
    }

#pragma unroll
    for (int ni = 0; ni < 4; ++ni) {
        const int col  = n0 + wn * 64 + ni * 16 + (lane & 15);
        const float bias = Wb[col] + Ub[col];
#pragma unroll
        for (int mi = 0; mi < 4; ++mi) {
            const int rowb = m0 + wm * 64 + mi * 16 + ((lane >> 4) * 4);
#pragma unroll
            for (int e = 0; e < 4; ++e)
                out[(size_t)(rowb + e) * 512 + col] = acc[mi][ni][e] + bias;
        }
    }
}

// ---------------------------------------------------------------------------
// Kernel 2: MFMA scan. Fragment layouts as validated by gemm_wx:
//   A-frag: row = lane&15, k = (lane>>4)*8 + e (8 contiguous f16)
//   B-frag: row(n) = lane&15, k same
//   D:      col(n) = lane&15, row(m) = (lane>>4)*4 + e
// ---------------------------------------------------------------------------
__global__ __launch_bounds__(512, 2)
void rnn_scan(float* __restrict__ out, const float* __restrict__ h0,
              const float* __restrict__ Uw) {
    __shared__ __align__(16) char Ul[512 * 256];   // U[n][k=384..512) f16, 128KB
    __shared__ __align__(16) char Hs[2][16 * 1024]; // H double buffer, 2x16KB

    const int tid  = threadIdx.x;
    const int wid  = tid >> 6;       // wave 0..7
    const int lane = tid & 63;
    const int l15  = lane & 15;
    const int l4   = lane >> 4;
    const int n0w  = wid * 64;       // this wave's N-range (4 tiles of 16)
    const int b0   = blockIdx.x * 16;
    const int aswz = (l15 & 7) << 4;

    // ---- U tail (k in [384,512)) -> LDS: 128 f16 = 256B = 16 x 8-float chunks.
    {
        const float4* src = reinterpret_cast<const float4*>(Uw + (size_t)tid * 512 + 384);
        const int sw = (tid & 7) << 4;
#pragma unroll
        for (int i = 0; i < 16; ++i) {
            f16x8 w = cvt8(src[2 * i], src[2 * i + 1]);
            *reinterpret_cast<f16x8*>(Ul + tid * 256 + ((16 * i) ^ sw)) = w;
        }
    }

    // ---- U main (k<384) -> reg B-fragments: u[kk][nt], kk=0..11, nt=0..3.
    f16x8 u[12][4];
#pragma unroll
    for (int kk = 0; kk < 12; ++kk)
#pragma unroll
        for (int nt = 0; nt < 4; ++nt) {
            const float4* p = reinterpret_cast<const float4*>(
                Uw + (size_t)(n0w + nt * 16 + l15) * 512 + kk * 32 + l4 * 8);
            u[kk][nt] = cvt8(p[0], p[1]);
        }

    // ---- h_0 -> Hs[0] (thread tid: batch m=tid>>5, 16-f16 chunk c=tid&31)
    {
        const int m = tid >> 5, c = tid & 31;
        const float4* p = reinterpret_cast<const float4*>(
            h0 + (size_t)(b0 + m) * 512 + c * 16);
        f16x8 w0 = cvt8(p[0], p[1]);
        f16x8 w1 = cvt8(p[2], p[3]);
        const int mb = m * 1024, sw = (m & 7) << 4;
        *reinterpret_cast<f16x8*>(Hs[0] + mb + ((c * 32) ^ sw)) = w0;
        *reinterpret_cast<f16x8*>(Hs[0] + mb + ((c * 32 + 16) ^ sw)) = w1;
    }

    // ---- per-lane byte offsets into out, one per m-row e (batch m = l4*4+e).
    float* const outg = out + (size_t)b0 * (T_STEPS * 512);
    int offe[4];
#pragma unroll
    for (int e = 0; e < 4; ++e)
        offe[e] = ((l4 * 4 + e) * (T_STEPS * 512) + (n0w + l15)) * 4;

    // ---- preload Wx row 0 (gemm_wx completed; same stream).
    float wx[4][4];
#pragma unroll
    for (int e = 0; e < 4; ++e) {
        const float* pe = reinterpret_cast<const float*>(
            reinterpret_cast<const char*>(outg) + offe[e]);
#pragma unroll
        for (int nt = 0; nt < 4; ++nt)
            wx[nt][e] = pe[nt * 16];
    }

    __syncthreads();

    const float C2L = -2.8853900817779268f;   // -2*log2(e)

    for (int t = 0; t < T_STEPS; ++t) {
        const char* const Hr = Hs[t & 1];
        char* const Hw = Hs[(t + 1) & 1];

        // Prefetch next step's Wx at step top: ~1 full step of latency cover;
        // loads are older than this step's h-stores in the vmcnt queue, so the
        // compiler's wait before next-step tanh is counted, never a drain.
        float wxn[4][4];
        if (t < T_STEPS - 1) {
#pragma unroll
            for (int e = 0; e < 4; ++e) {
                const float* pe = reinterpret_cast<const float*>(
                    reinterpret_cast<const char*>(outg) + offe[e] + 2048);
#pragma unroll
                for (int nt = 0; nt < 4; ++nt)
                    wxn[nt][e] = pe[nt * 16];
            }
        }

        // MFMA phase: acc[nt] += A(kk) * U(kk,nt) over 16 k-steps.
        f32x4 acc[4];
#pragma unroll
        for (int nt = 0; nt < 4; ++nt) acc[nt] = (f32x4){0.f, 0.f, 0.f, 0.f};
#pragma unroll
        for (int kk = 0; kk < 16; ++kk) {
            const f16x8 a = *reinterpret_cast<const f16x8*>(
                Hr + l15 * 1024 + ((kk * 64 + l4 * 16) ^ aswz));
            if (kk < 12) {
#pragma unroll
                for (int nt = 0; nt < 4; ++nt)
                    acc[nt] = __builtin_amdgcn_mfma_f32_16x16x32_f16(
                        a, u[kk][nt], acc[nt], 0, 0, 0);
            } else {
#pragma unroll
                for (int nt = 0; nt < 4; ++nt) {
                    const f16x8 bb = *reinterpret_cast<const f16x8*>(
                        Ul + (size_t)(n0w + nt * 16 + l15) * 256 +
                        (((kk - 12) * 64 + l4 * 16) ^ aswz));
                    acc[nt] = __builtin_amdgcn_mfma_f32_16x16x32_f16(
                        a, bb, acc[nt], 0, 0, 0);
                }
            }
        }

        // tanh: s=exp2(-2log2e*|a|), r=(1-s)/(1+s), restore sign.
        float hv[4][4];
#pragma unroll
        for (int nt = 0; nt < 4; ++nt)
#pragma unroll
            for (int e = 0; e < 4; ++e) {
                const float aa = acc[nt][e] + wx[nt][e];   // U_b already in wx
                const float ss = exp2f(C2L * fabsf(aa));
                const float r  = (1.0f - ss) / (1.0f + ss);
                hv[nt][e] = copysignf(r, aa);
            }

        // h(t) -> out (overwrites consumed Wx row).
#pragma unroll
        for (int e = 0; e < 4; ++e) {
            float* pe = reinterpret_cast<float*>(
                reinterpret_cast<char*>(outg) + offe[e]);
#pragma unroll
            for (int nt = 0; nt < 4; ++nt)
                pe[nt * 16] = hv[nt][e];
            offe[e] += 2048;
        }

        // H(t) -> Hs write buffer (other buffer than the one being read:
        // no read-write hazard, so no pre-write barrier needed).
#pragma unroll
        for (int nt = 0; nt < 4; ++nt) {
            const int j2 = 2 * (n0w + nt * 16 + l15);
#pragma unroll
            for (int e = 0; e < 4; ++e) {
                const int m = l4 * 4 + e;
                *reinterpret_cast<f16*>(Hw + m * 1024 + (j2 ^ ((m & 7) << 4))) =
                    (f16)hv[nt][e];
            }
        }

        // ONE barrier per step: H(t) writes drained (lgkmcnt only — vmcnt NOT
        // drained, h-stores stay in flight), then sync.
        asm volatile("s_waitcnt lgkmcnt(0)\n\ts_barrier" ::: "memory");

#pragma unroll
        for (int e = 0; e < 4; ++e)
#pragma unroll
            for (int nt = 0; nt < 4; ++nt)
                wx[nt][e] = wxn[nt][e];
    }
}

// ---------------------------------------------------------------------------
extern "C" void kernel_launch(void* const* d_in, const int* in_sizes, int n_in,
                              void* d_out, int out_size, void* d_ws, size_t ws_size,
                              hipStream_t stream) {
    const float* X  = (const float*)d_in[0];
    const float* h0 = (const float*)d_in[1];
    const float* Ww = (const float*)d_in[2];
    const float* Wb = (const float*)d_in[3];
    const float* Uw = (const float*)d_in[4];
    const float* Ub = (const float*)d_in[5];
    float* out = (float*)d_out;

    gemm_wx<<<dim3(512, 4), dim3(256), 0, stream>>>(X, Ww, Wb, Ub, out);
    rnn_scan<<<dim3(4), dim3(512), 0, stream>>>(out, h0, Uw);
}

// Round 9
// 2338.426 us; speedup vs baseline: 2.9298x; 2.1507x over previous
//
#include <hip/hip_runtime.h>
#include <cstdint>
#include <cstddef>

// RNNLayer: B=64, T=1024, IN=512, H=512, fp32 in/out.
// Phase 1: Wx = X @ W_w^T + (W_b + U_b)  (f16 MFMA GEMM) -> d_out.
// Phase 2: VALU scan, one WG (512 threads, 8 waves) per batch, 64 CUs.
//   Thread j owns output row j: 256 v_dot2_f32_f16 per step (builtin fdot2 —
//   round 8's inline-asm dot2 with an "s" operand constraint was numerically
//   wrong; reverted to the round-3-proven builtin path).
//   U[j, 0:416) = 208 f16x2 ints in VGPRs (208 + ~30 working set = ~240,
//   fits the 256-reg cap of launch_bounds(512,2) -- round 3's 224 did not).
//   U[j, 416:512) = 48 pairs in LDS, COLUMN-major Ut32[pair][tid], read as
//   ds_read_b32 (bank = tid%32 -> 2 lanes/bank, conflict-free; round 8's
//   row-major b128 layout was an 8-way bank conflict).
//   h broadcast: one b128 LDS read/lane gathers all 512 h, readlane -> dot2.
//   One barrier/step (raw lgkmcnt+s_barrier, proven round 7), h double-buffered.

#define T_STEPS 1024
#define NPV 208                 // u pairs in VGPRs (k < 416)
#define NTP 48                  // tail pairs in LDS  (k in [416,512))

using f16 = _Float16;
typedef f16  f16x2 __attribute__((ext_vector_type(2)));
typedef f16  f16x8 __attribute__((ext_vector_type(8)));
typedef float f32x4 __attribute__((ext_vector_type(4)));

#if __has_builtin(__builtin_amdgcn_fdot2)
#define FDOT2(a, b, c) __builtin_amdgcn_fdot2((a), (b), (c), false)
#else
static __device__ __forceinline__ float FDOT2(f16x2 a, f16x2 b, float c) {
    return c + (float)a[0] * (float)b[0] + (float)a[1] * (float)b[1];
}
#endif

static __device__ __forceinline__ f16x8 cvt8(float4 v0, float4 v1) {
    return (f16x8){ (f16)v0.x, (f16)v0.y, (f16)v0.z, (f16)v0.w,
                    (f16)v1.x, (f16)v1.y, (f16)v1.z, (f16)v1.w };
}
static __device__ __forceinline__ int pack2(float2 v) {
    f16x2 p = { (f16)v.x, (f16)v.y };
    return __builtin_bit_cast(int, p);
}
static __device__ __forceinline__ f16x2 asf16x2(int v) {
    return __builtin_bit_cast(f16x2, v);
}

// ---------------------------------------------------------------------------
// Kernel 1: Wx GEMM (bias includes U_b). Unchanged (proven).
// ---------------------------------------------------------------------------
__global__ __launch_bounds__(256, 2)
void gemm_wx(const float* __restrict__ X, const float* __restrict__ W,
             const float* __restrict__ Wb, const float* __restrict__ Ub,
             float* __restrict__ out) {
    __shared__ __align__(16) char Al[128 * 128];
    __shared__ __align__(16) char Bl[128 * 128];

    const int tid  = threadIdx.x;
    const int lane = tid & 63;
    const int wid  = tid >> 6;
    const int wm   = wid & 1;
    const int wn   = wid >> 1;
    const int m0   = blockIdx.x * 128;
    const int n0   = blockIdx.y * 128;

    f32x4 acc[4][4] = {};

    for (int kt = 0; kt < 512; kt += 64) {
        __syncthreads();
#pragma unroll
        for (int i = 0; i < 4; ++i) {
            const int id   = tid + i * 256;
            const int row  = id >> 3;
            const int slot = id & 7;
            const float4* pa = reinterpret_cast<const float4*>(
                X + (size_t)(m0 + row) * 512 + kt + slot * 8);
            const float4* pb = reinterpret_cast<const float4*>(
                W + (size_t)(n0 + row) * 512 + kt + slot * 8);
            f16x8 va = cvt8(pa[0], pa[1]);
            f16x8 vb = cvt8(pb[0], pb[1]);
            const int cb = (slot * 16) ^ ((row & 7) << 4);
            *reinterpret_cast<f16x8*>(Al + row * 128 + cb) = va;
            *reinterpret_cast<f16x8*>(Bl + row * 128 + cb) = vb;
        }
        __syncthreads();

#pragma unroll
        for (int kk = 0; kk < 2; ++kk) {
            f16x8 af[4], bf[4];
#pragma unroll
            for (int mi = 0; mi < 4; ++mi) {
                const int r  = wm * 64 + mi * 16 + (lane & 15);
                const int cb = (kk * 64 + ((lane >> 4) * 16)) ^ ((r & 7) << 4);
                af[mi] = *reinterpret_cast<const f16x8*>(Al + r * 128 + cb);
            }
#pragma unroll
            for (int ni = 0; ni < 4; ++ni) {
                const int r  = wn * 64 + ni * 16 + (lane & 15);
                const int cb = (kk * 64 + ((lane >> 4) * 16)) ^ ((r & 7) << 4);
                bf[ni] = *reinterpret_cast<const f16x8*>(Bl + r * 128 + cb);
            }
#pragma unroll
            for (int mi = 0; mi < 4; ++mi)
#pragma unroll
                for (int ni = 0; ni < 4; ++ni)
                    acc[mi][ni] = __builtin_amdgcn_mfma_f32_16x16x32_f16(
                        af[mi], bf[ni], acc[mi][ni], 0, 0, 0);
        }
    }

#pragma unroll
    for (int ni = 0; ni < 4; ++ni) {
        const int col  = n0 + wn * 64 + ni * 16 + (lane & 15);
        const float bias = Wb[col] + Ub[col];
#pragma unroll
        for (int mi = 0; mi < 4; ++mi) {
            const int rowb = m0 + wm * 64 + mi * 16 + ((lane >> 4) * 4);
#pragma unroll
            for (int e = 0; e < 4; ++e)
                out[(size_t)(rowb + e) * 512 + col] = acc[mi][ni][e] + bias;
        }
    }
}

// ---------------------------------------------------------------------------
// Kernel 2: VALU scan.
// ---------------------------------------------------------------------------
__global__ __launch_bounds__(512, 2)
void rnn_scan(float* __restrict__ out, const float* __restrict__ h0,
              const float* __restrict__ Uw) {
    __shared__ __align__(16) int  Ut32[NTP * 512];  // tail pairs, col-major, 96KB
    __shared__ __align__(16) char hb[2][1024];      // h as f16[512], dbuf

    const int tid  = threadIdx.x;    // = output row j
    const int b    = blockIdx.x;
    const int lane = tid & 63;

    // ---- U[j, 0:416) -> 208 packed-f16x2 ints (fits arch-VGPR budget).
    const float2* up = reinterpret_cast<const float2*>(Uw + (size_t)tid * 512);
    int uv[NPV];
#pragma unroll
    for (int p = 0; p < NPV; ++p)
        uv[p] = pack2(up[p]);

    // ---- U[j, 416:512) -> LDS column-major: Ut32[pair c][tid].
    {
        const float2* tp = reinterpret_cast<const float2*>(
            Uw + (size_t)tid * 512 + 416);
#pragma unroll
        for (int c = 0; c < NTP; ++c)
            Ut32[c * 512 + tid] = pack2(tp[c]);
    }

    // ---- h_0 -> hb[0] (f16 linear; lane l later gathers pairs 4l..4l+3).
    *reinterpret_cast<f16*>(hb[0] + 2 * tid) = (f16)h0[b * 512 + tid];

    float* const obase = out + (size_t)b * (T_STEPS * 512);
    float wx = obase[tid];           // Wx row 0 (gemm_wx done; same stream)
    __syncthreads();

    for (int t = 0; t < T_STEPS; ++t) {
        // Full h_{t-1} gathered into the wave: lane l holds pairs 4l..4l+3.
        const uint4 vh = *reinterpret_cast<const uint4*>(hb[t & 1] + 16 * lane);
        // Prefetch next step's Wx (~1 step of latency cover).
        float wxn = 0.0f;
        if (t < T_STEPS - 1) wxn = obase[(size_t)(t + 1) * 512 + tid];

        float a0 = 0.f, a1 = 0.f, a2 = 0.f, a3 = 0.f;

        // Register part: pairs 0..207 (k < 416). Pair q: lane q>>2, comp q&3.
#pragma unroll
        for (int q4 = 0; q4 < NPV / 4; ++q4) {
            const int h0_ = __builtin_amdgcn_readlane((int)vh.x, q4);
            const int h1_ = __builtin_amdgcn_readlane((int)vh.y, q4);
            const int h2_ = __builtin_amdgcn_readlane((int)vh.z, q4);
            const int h3_ = __builtin_amdgcn_readlane((int)vh.w, q4);
            a0 = FDOT2(asf16x2(uv[4 * q4 + 0]), asf16x2(h0_), a0);
            a1 = FDOT2(asf16x2(uv[4 * q4 + 1]), asf16x2(h1_), a1);
            a2 = FDOT2(asf16x2(uv[4 * q4 + 2]), asf16x2(h2_), a2);
            a3 = FDOT2(asf16x2(uv[4 * q4 + 3]), asf16x2(h3_), a3);
        }
        // Tail: pairs 208..255 (k in [416,512)), U pairs via conflict-free b32.
#pragma unroll
        for (int c = 0; c < NTP; c += 4) {
            const int ln  = NPV / 4 + (c >> 2);
            const int h0_ = __builtin_amdgcn_readlane((int)vh.x, ln);
            const int h1_ = __builtin_amdgcn_readlane((int)vh.y, ln);
            const int h2_ = __builtin_amdgcn_readlane((int)vh.z, ln);
            const int h3_ = __builtin_amdgcn_readlane((int)vh.w, ln);
            a0 = FDOT2(asf16x2(Ut32[(c + 0) * 512 + tid]), asf16x2(h0_), a0);
            a1 = FDOT2(asf16x2(Ut32[(c + 1) * 512 + tid]), asf16x2(h1_), a1);
            a2 = FDOT2(asf16x2(Ut32[(c + 2) * 512 + tid]), asf16x2(h2_), a2);
            a3 = FDOT2(asf16x2(Ut32[(c + 3) * 512 + tid]), asf16x2(h3_), a3);
        }

        // tanh (round-2/3 proven form).
        const float aa = ((a0 + a1) + (a2 + a3)) + wx;   // U_b folded into Wx
        const float ax = fabsf(aa);
        const float e  = __expf(2.0f * ax);
        const float r1 = 1.0f - 2.0f / (e + 1.0f);       // tanh(|aa|); e=inf -> 1
        const float h  = copysignf(r1, aa);

        obase[(size_t)t * 512 + tid] = h;          // overwrite consumed Wx
        *reinterpret_cast<f16*>(hb[(t + 1) & 1] + 2 * tid) = (f16)h;
        wx = wxn;

        // One barrier: h(t) LDS write drained (lgkmcnt only; global stores
        // stay in flight), then all waves step together.
        asm volatile("s_waitcnt lgkmcnt(0)\n\ts_barrier" ::: "memory");
    }
}

// ---------------------------------------------------------------------------
extern "C" void kernel_launch(void* const* d_in, const int* in_sizes, int n_in,
                              void* d_out, int out_size, void* d_ws, size_t ws_size,
                              hipStream_t stream) {
    const float* X  = (const float*)d_in[0];
    const float* h0 = (const float*)d_in[1];
    const float* Ww = (const float*)d_in[2];
    const float* Wb = (const float*)d_in[3];
    const float* Uw = (const float*)d_in[4];
    const float* Ub = (const float*)d_in[5];
    float* out = (float*)d_out;

    gemm_wx<<<dim3(512, 4), dim3(256), 0, stream>>>(X, Ww, Wb, Ub, out);
    rnn_scan<<<dim3(64), dim3(512), 0, stream>>>(out, h0, Uw);
}